// Round 7
// baseline (140.812 us; speedup 1.0000x reference)
//
#include <hip/hip_runtime.h>
#include <stdint.h>

// Problem constants (match reference)
#define B_ 4096
#define C_ 200
#define P_ 32
#define F_ 512
#define N_ (C_*P_)        // 6400 prototypes total
#define ALPHA_ 5.0
#define EPS_ 1e-8

typedef unsigned char u8;
typedef __attribute__((ext_vector_type(4))) float floatx4;  // MFMA C/D frag

union frag16 { int4 v; long l[2]; };   // 16 fp8 = two MFMA k-slices (virtual-K)

// ---------- prep: fp32 -> fp8 e4m3 in MFMA-native packed layout ----------
// Packed layout (per matrix): o = tm*512 + kc*64 + q*16 + r  (16-B units), i.e. byte
// offset (tm*8+kc)*1024 + (q*16+r)*16 holds features [kc*64+q*16, +16) of row tm*16+r.
// Thread t = output unit o: writes are wave-contiguous (1KB/wave); reads are per-lane
// 64B-aligned 64B loads (native cache granule) — no fragmented write-combining.
__global__ void prep_kernel(const float* __restrict__ outputs, const float* __restrict__ clusters,
                            u8* __restrict__ At, u8* __restrict__ Bt) {
    int t = blockIdx.x * 256 + threadIdx.x;
    const float* src; u8* dst; int o;
    if (t < B_ * 32) { o = t;           src = outputs;  dst = At; }
    else             { o = t - B_ * 32; src = clusters; dst = Bt; }
    const int tm = o >> 9, kc = (o >> 6) & 7, q = (o >> 4) & 3, r = o & 15;
    const float4* s = (const float4*)(src + (size_t)(tm * 16 + r) * F_ + kc * 64 + q * 16);
    float4 v0 = s[0], v1 = s[1], v2 = s[2], v3 = s[3];
    int4 w;
    w.x = __builtin_amdgcn_cvt_pk_fp8_f32(v0.x, v0.y, 0, false);
    w.x = __builtin_amdgcn_cvt_pk_fp8_f32(v0.z, v0.w, w.x, true);
    w.y = __builtin_amdgcn_cvt_pk_fp8_f32(v1.x, v1.y, 0, false);
    w.y = __builtin_amdgcn_cvt_pk_fp8_f32(v1.z, v1.w, w.y, true);
    w.z = __builtin_amdgcn_cvt_pk_fp8_f32(v2.x, v2.y, 0, false);
    w.z = __builtin_amdgcn_cvt_pk_fp8_f32(v2.z, v2.w, w.z, true);
    w.w = __builtin_amdgcn_cvt_pk_fp8_f32(v3.x, v3.y, 0, false);
    w.w = __builtin_amdgcn_cvt_pk_fp8_f32(v3.z, v3.w, w.w, true);
    *(int4*)(dst + (size_t)o * 16) = w;
}

// p2[n] = sum_f clusters[n][f]^2 in fp32 (one wave per prototype row) — validated R2 version
__global__ void p2_kernel(const float* __restrict__ clusters, float* __restrict__ p2) {
    int row  = blockIdx.x * 4 + (threadIdx.x >> 6);
    int lane = threadIdx.x & 63;
    const float4* r = (const float4*)(clusters + (size_t)row * F_);
    float s = 0.f;
#pragma unroll
    for (int i = 0; i < 2; ++i) {
        float4 v = r[lane + i * 64];
        s += v.x*v.x + v.y*v.y + v.z*v.z + v.w*v.w;
    }
#pragma unroll
    for (int m = 32; m >= 1; m >>= 1) s += __shfl_xor(s, m);
    if (lane == 0) p2[row] = s;
}

// ---------- score kernel: fp8 MFMA GEMM, 3-buffer LDS ring, depth-2 prefetch ----------
// AITER-style: raw s_barrier + manual s_waitcnt vmcnt(4) — waits only the OLDEST stage's
// loads; the next stage's 4 gld16 stay in flight across the barrier (vmcnt never 0 until
// the tail). One barrier/stage, no full drain.
#define BM 128
#define BN 128

typedef const __attribute__((address_space(1))) unsigned int gu32_t;
typedef __attribute__((address_space(3))) unsigned int lu32_t;

__device__ __forceinline__ void gld16(const u8* g, u8* l) {
    __builtin_amdgcn_global_load_lds((gu32_t*)g, (lu32_t*)l, 16, 0, 0);
}
// s_waitcnt imm (gfx9): vmcnt[3:0] | expcnt<<4 | lgkmcnt<<8 | vmcnt[5:4]<<14
__device__ __forceinline__ void wait_vm4() { __builtin_amdgcn_s_waitcnt(0xF74); } // vmcnt(4)
__device__ __forceinline__ void wait_vm0() { __builtin_amdgcn_s_waitcnt(0xF70); } // vmcnt(0)

__global__ __launch_bounds__(256, 3)
void score_kernel(const u8* __restrict__ At, const u8* __restrict__ Bt,
                  const float* __restrict__ p2,
                  float* __restrict__ min_d, int* __restrict__ min_idx) {
    __shared__ __align__(16) u8 lds[3][16384];  // ring: [buf][ A 8x1KB | B 8x1KB ]

    const int tid  = threadIdx.x;
    const int lane = tid & 63;
    const int w    = tid >> 6;          // wave 0..3 (2x2 wave grid, 64x64 per wave)
    const int wm   = w >> 1, wn = w & 1;
    const int bx   = blockIdx.x;        // n-tile 0..49
    const int by   = blockIdx.y;        // m-tile 0..31
    const int m0   = by * BM, n0 = bx * BN;
    const int mrow = lane & 15;
    const int quad = lane >> 4;
    const int l16  = lane * 16;

    const u8* ag = At + ((size_t)(by * 8) << 13) + l16;   // 8 row-tiles x 8KB
    const u8* bg = Bt + ((size_t)(bx * 8) << 13) + l16;

    floatx4 zf = {0.f, 0.f, 0.f, 0.f};
    floatx4 acc[4][4];
#pragma unroll
    for (int i = 0; i < 4; ++i)
#pragma unroll
        for (int j = 0; j < 4; ++j) acc[i][j] = zf;

    // issue stage k's 4 per-wave loads into ring buffer b
    #define ISSUE(k, b)                                                        \
        gld16(ag + ((w * 8 + (k)) << 10),       lds[b] + w * 1024);            \
        gld16(ag + (((w + 4) * 8 + (k)) << 10), lds[b] + (w + 4) * 1024);      \
        gld16(bg + ((w * 8 + (k)) << 10),       lds[b] + 8192 + w * 1024);     \
        gld16(bg + (((w + 4) * 8 + (k)) << 10), lds[b] + 8192 + (w + 4) * 1024);

    ISSUE(0, 0)
    ISSUE(1, 1)

#pragma unroll
    for (int kc = 0; kc < 8; ++kc) {
        const int cur = kc % 3;
        if (kc < 7) wait_vm4(); else wait_vm0();   // oldest stage's loads landed
        __builtin_amdgcn_s_barrier();              // raw barrier: no vmcnt(0) drain
        if (kc < 6) { const int nb = (kc + 2) % 3; ISSUE(kc + 2, nb) }

        frag16 a[4], b[4];
#pragma unroll
        for (int t = 0; t < 4; ++t) {
            a[t].v = *(const int4*)(lds[cur] + (wm * 4 + t) * 1024 + l16);
            b[t].v = *(const int4*)(lds[cur] + 8192 + (wn * 4 + t) * 1024 + l16);
        }
#pragma unroll
        for (int s = 0; s < 2; ++s)
#pragma unroll
            for (int mt = 0; mt < 4; ++mt)
#pragma unroll
                for (int nt = 0; nt < 4; ++nt)
                    acc[mt][nt] = __builtin_amdgcn_mfma_f32_16x16x32_fp8_fp8(
                        a[mt].l[s], b[nt].l[s], acc[mt][nt], 0, 0, 0);
    }
    #undef ISSUE

    // Epilogue: score = p2[n] - 2*xp (x2 dropped: constant per row b, argmins unchanged).
    // C/D layout: col = lane&15, row = quad*4 + reg. Each wave: 64 rows x 2 classes.
    float pg[4];
#pragma unroll
    for (int nt = 0; nt < 4; ++nt) pg[nt] = p2[n0 + wn * 64 + nt * 16 + mrow];

#pragma unroll
    for (int ch = 0; ch < 2; ++ch) {
        const int cls = bx * 4 + wn * 2 + ch;
#pragma unroll
        for (int mt = 0; mt < 4; ++mt)
#pragma unroll
            for (int reg = 0; reg < 4; ++reg) {
                float v0 = pg[ch * 2]     - 2.0f * acc[mt][ch * 2][reg];     // p = mrow
                float v1 = pg[ch * 2 + 1] - 2.0f * acc[mt][ch * 2 + 1][reg]; // p = 16+mrow
                float v; int pi;
                if (v1 < v0) { v = v1; pi = 16 + mrow; } else { v = v0; pi = mrow; }
#pragma unroll
                for (int m = 8; m >= 1; m >>= 1) {
                    float ov = __shfl_xor(v, m);
                    int   oi = __shfl_xor(pi, m);
                    if (ov < v || (ov == v && oi < pi)) { v = ov; pi = oi; }
                }
                if (mrow == 0) {
                    int grow = m0 + wm * 64 + mt * 16 + quad * 4 + reg;
                    min_d[grow * C_ + cls]   = v;
                    min_idx[grow * C_ + cls] = pi;
                }
            }
    }
}

// ---------- per-sample selection + exact fp32 distances (no atomics) ----------
__global__ void select_kernel(const float* __restrict__ X, const float* __restrict__ clusters,
                              const int* __restrict__ tgt, const float* __restrict__ min_d,
                              const int* __restrict__ min_idx,
                              float* __restrict__ stw, float* __restrict__ sww) {
    int b    = blockIdx.x * 4 + (threadIdx.x >> 6);
    int lane = threadIdx.x & 63;
    int tc   = tgt[b];

    float bv = 3.4e38f; int bc = 1 << 30;
    for (int c = lane; c < C_; c += 64) {
        float v = min_d[b * C_ + c];
        if (c != tc && (v < bv || (v == bv && c < bc))) { bv = v; bc = c; }
    }
#pragma unroll
    for (int m = 32; m >= 1; m >>= 1) {
        float ov = __shfl_xor(bv, m);
        int   oc = __shfl_xor(bc, m);
        if (ov < bv || (ov == bv && oc < bc)) { bv = ov; bc = oc; }
    }
    int ap = min_idx[b * C_ + tc];   // best proto in target class
    int wp = min_idx[b * C_ + bc];   // best proto in nearest wrong class

    const float4* xb = (const float4*)(X + (size_t)b * F_);
    const float4* pa = (const float4*)(clusters + ((size_t)tc * P_ + ap) * F_);
    const float4* pw = (const float4*)(clusters + ((size_t)bc * P_ + wp) * F_);
    float st = 0.f, sw = 0.f;
#pragma unroll
    for (int i = 0; i < 2; ++i) {
        float4 x = xb[lane + i * 64], a = pa[lane + i * 64], ww = pw[lane + i * 64];
        float dx = x.x - a.x, dy = x.y - a.y, dz = x.z - a.z, dw = x.w - a.w;
        st += dx*dx + dy*dy + dz*dz + dw*dw;
        dx = x.x - ww.x; dy = x.y - ww.y; dz = x.z - ww.z; dw = x.w - ww.w;
        sw += dx*dx + dy*dy + dz*dz + dw*dw;
    }
#pragma unroll
    for (int m = 32; m >= 1; m >>= 1) { st += __shfl_xor(st, m); sw += __shfl_xor(sw, m); }
    if (lane == 0) { stw[b] = st; sww[b] = sw; }
}

// Single-block reduction of 2x4096 floats + final loss
__global__ __launch_bounds__(1024)
void finalize_kernel(const float* __restrict__ stw, const float* __restrict__ sww,
                     float* __restrict__ out) {
    __shared__ float r1[16], r2[16];
    int tid = threadIdx.x;
    float s1 = 0.f, s2 = 0.f;
#pragma unroll
    for (int i = 0; i < 4; ++i) {
        s1 += stw[tid + i * 1024];
        s2 += sww[tid + i * 1024];
    }
#pragma unroll
    for (int m = 32; m >= 1; m >>= 1) { s1 += __shfl_xor(s1, m); s2 += __shfl_xor(s2, m); }
    if ((tid & 63) == 0) { r1[tid >> 6] = s1; r2[tid >> 6] = s2; }
    __syncthreads();
    if (tid == 0) {
        double t1 = 0.0, t2 = 0.0;
#pragma unroll
        for (int i = 0; i < 16; ++i) { t1 += (double)r1[i]; t2 += (double)r2[i]; }
        double denom = (double)B_ * (double)F_;
        double tl  = t1 / denom;
        double ntl = t2 / denom;
        out[0] = (float)((1.0 - ALPHA_) * tl + ALPHA_ / (ntl + EPS_));
    }
}

// ---------- launch ----------
extern "C" void kernel_launch(void* const* d_in, const int* in_sizes, int n_in,
                              void* d_out, int out_size, void* d_ws, size_t ws_size,
                              hipStream_t stream) {
    const float* outputs  = (const float*)d_in[0];
    const float* clusters = (const float*)d_in[1];
    const int*   tgt      = (const int*)d_in[2];
    float* out = (float*)d_out;

    char* ws = (char*)d_ws;
    // workspace layout (16B-aligned), total 11,953,152 bytes
    u8*     At      = (u8*)(ws);                     // packed A: 256*8*1024 = 2,097,152
    u8*     Bt      = (u8*)(ws + 2097152);           // packed B: 400*8*1024 = 3,276,800
    float*  p2      = (float*)(ws + 5373952);        // 6400*4      =    25,600
    float*  min_d   = (float*)(ws + 5399552);        // 4096*200*4  = 3,276,800
    int*    min_idx = (int*)(ws + 8676352);          // 4096*200*4  = 3,276,800
    // per-sample partials: reuse the At region (dead after score_kernel)
    float*  stw     = (float*)(ws);                  // 4096*4 = 16 KB
    float*  sww     = (float*)(ws + 16384);          // 4096*4 = 16 KB

    prep_kernel<<<(B_ * 32 + N_ * 32) / 256, 256, 0, stream>>>(outputs, clusters, At, Bt); // 1312 blocks
    p2_kernel<<<N_ / 4, 256, 0, stream>>>(clusters, p2);                                   // 1600 blocks
    score_kernel<<<dim3(N_ / BN, B_ / BM), 256, 0, stream>>>(At, Bt, p2, min_d, min_idx);
    select_kernel<<<B_ / 4, 256, 0, stream>>>(outputs, clusters, tgt, min_d, min_idx, stw, sww);
    finalize_kernel<<<1, 1024, 0, stream>>>(stw, sww, out);
}

// Round 8
// 110.152 us; speedup vs baseline: 1.2783x; 1.2783x over previous
//
#include <hip/hip_runtime.h>
#include <stdint.h>

// Problem constants (match reference)
#define B_ 4096
#define C_ 200
#define P_ 32
#define F_ 512
#define N_ (C_*P_)        // 6400 prototypes total
#define ALPHA_ 5.0
#define EPS_ 1e-8
#define NROWS_ (B_ + N_)  // 10496 sumsq rows (x2 then p2)

typedef unsigned char u8;
typedef __attribute__((ext_vector_type(4))) float floatx4;  // MFMA C/D frag

union frag16 { int4 v; long l[2]; };   // 16 fp8 = two MFMA k-slices (virtual-K)

__global__ void zero_kernel(float* __restrict__ sumsq) {
    sumsq[blockIdx.x * 256 + threadIdx.x] = 0.f;   // 41*256 = 10496 exactly
}

// ---------- prep: fp32 -> fp8 e4m3 packed + row sum-of-squares (x2 | p2) ----------
// Packed layout: o = tm*512 + kc*64 + q*16 + r (16-B units); byte (tm*8+kc)*1024 +
// (q*16+r)*16 holds features [kc*64+q*16,+16) of row tm*16+r. Output-indexed: writes
// wave-contiguous 1KB, reads per-lane 64B-aligned. One wave = one (tm,kc); lanes with
// equal r (q=0..3 at lane r+16q) reduce to a row-chunk sumsq, atomically accumulated.
__global__ void prep_kernel(const float* __restrict__ outputs, const float* __restrict__ clusters,
                            u8* __restrict__ At, u8* __restrict__ Bt, float* __restrict__ sumsq) {
    int t = blockIdx.x * 256 + threadIdx.x;
    const float* src; u8* dst; int o, rbase;
    if (t < B_ * 32) { o = t;           src = outputs;  dst = At; rbase = 0; }
    else             { o = t - B_ * 32; src = clusters; dst = Bt; rbase = B_; }
    const int tm = o >> 9, kc = (o >> 6) & 7, q = (o >> 4) & 3, r = o & 15;
    const int row = tm * 16 + r;
    const float4* s = (const float4*)(src + (size_t)row * F_ + kc * 64 + q * 16);
    float4 v0 = s[0], v1 = s[1], v2 = s[2], v3 = s[3];
    int4 w;
    w.x = __builtin_amdgcn_cvt_pk_fp8_f32(v0.x, v0.y, 0, false);
    w.x = __builtin_amdgcn_cvt_pk_fp8_f32(v0.z, v0.w, w.x, true);
    w.y = __builtin_amdgcn_cvt_pk_fp8_f32(v1.x, v1.y, 0, false);
    w.y = __builtin_amdgcn_cvt_pk_fp8_f32(v1.z, v1.w, w.y, true);
    w.z = __builtin_amdgcn_cvt_pk_fp8_f32(v2.x, v2.y, 0, false);
    w.z = __builtin_amdgcn_cvt_pk_fp8_f32(v2.z, v2.w, w.z, true);
    w.w = __builtin_amdgcn_cvt_pk_fp8_f32(v3.x, v3.y, 0, false);
    w.w = __builtin_amdgcn_cvt_pk_fp8_f32(v3.z, v3.w, w.w, true);
    *(int4*)(dst + (size_t)o * 16) = w;

    float ss = v0.x*v0.x + v0.y*v0.y + v0.z*v0.z + v0.w*v0.w
             + v1.x*v1.x + v1.y*v1.y + v1.z*v1.z + v1.w*v1.w
             + v2.x*v2.x + v2.y*v2.y + v2.z*v2.z + v2.w*v2.w
             + v3.x*v3.x + v3.y*v3.y + v3.z*v3.z + v3.w*v3.w;
    ss += __shfl_xor(ss, 16);
    ss += __shfl_xor(ss, 32);
    if ((o & 63) < 16) atomicAdd(&sumsq[rbase + row], ss);   // 16 lanes, 16 consecutive rows
}

// ---------- score kernel: fp8 MFMA GEMM, LDS double-buffer, 1-stage-ahead prefetch ----------
// (R6 structure, proven 54us: one __syncthreads per stage; prefetch of kc+1 issued before
// consuming kc so the barrier's vmcnt drain is partially pre-paid.)
#define BM 128
#define BN 128

typedef const __attribute__((address_space(1))) unsigned int gu32_t;
typedef __attribute__((address_space(3))) unsigned int lu32_t;

__device__ __forceinline__ void gld16(const u8* g, u8* l) {
    __builtin_amdgcn_global_load_lds((gu32_t*)g, (lu32_t*)l, 16, 0, 0);
}

__global__ __launch_bounds__(256, 4)
void score_kernel(const u8* __restrict__ At, const u8* __restrict__ Bt,
                  const float* __restrict__ p2, float* __restrict__ min_d) {
    __shared__ __align__(16) u8 lds[2][16384];   // [buf][ A: 8 tiles x 1KB | B: 8 tiles x 1KB ]

    const int tid  = threadIdx.x;
    const int lane = tid & 63;
    const int w    = tid >> 6;          // wave 0..3 (2x2 wave grid, 64x64 per wave)
    const int wm   = w >> 1, wn = w & 1;
    const int bx   = blockIdx.x;        // n-tile 0..49
    const int by   = blockIdx.y;        // m-tile 0..31
    const int m0   = by * BM, n0 = bx * BN;
    const int mrow = lane & 15;
    const int quad = lane >> 4;
    const int l16  = lane * 16;

    const u8* ag = At + ((size_t)(by * 8) << 13);   // 8 row-tiles x 8KB each
    const u8* bg = Bt + ((size_t)(bx * 8) << 13);

    floatx4 zf = {0.f, 0.f, 0.f, 0.f};
    floatx4 acc[4][4];
#pragma unroll
    for (int i = 0; i < 4; ++i)
#pragma unroll
        for (int j = 0; j < 4; ++j) acc[i][j] = zf;

    // prologue: prefetch stage 0 into buf 0 (wave w loads A tiles {w,w+4}, B tiles {w,w+4})
    gld16(ag + ((w * 8) << 10) + l16,           lds[0] + w * 1024);
    gld16(ag + (((w + 4) * 8) << 10) + l16,     lds[0] + (w + 4) * 1024);
    gld16(bg + ((w * 8) << 10) + l16,           lds[0] + 8192 + w * 1024);
    gld16(bg + (((w + 4) * 8) << 10) + l16,     lds[0] + 8192 + (w + 4) * 1024);
    __syncthreads();

#pragma unroll
    for (int kc = 0; kc < 8; ++kc) {
        const int cur = kc & 1;
        if (kc < 7) {
            const int nb = cur ^ 1, kn = kc + 1;
            gld16(ag + ((w * 8 + kn) << 10) + l16,         lds[nb] + w * 1024);
            gld16(ag + (((w + 4) * 8 + kn) << 10) + l16,   lds[nb] + (w + 4) * 1024);
            gld16(bg + ((w * 8 + kn) << 10) + l16,         lds[nb] + 8192 + w * 1024);
            gld16(bg + (((w + 4) * 8 + kn) << 10) + l16,   lds[nb] + 8192 + (w + 4) * 1024);
        }
        frag16 a[4], b[4];
#pragma unroll
        for (int t = 0; t < 4; ++t) {
            a[t].v = *(const int4*)(lds[cur] + (wm * 4 + t) * 1024 + l16);
            b[t].v = *(const int4*)(lds[cur] + 8192 + (wn * 4 + t) * 1024 + l16);
        }
#pragma unroll
        for (int s = 0; s < 2; ++s)
#pragma unroll
            for (int mt = 0; mt < 4; ++mt)
#pragma unroll
                for (int nt = 0; nt < 4; ++nt)
                    acc[mt][nt] = __builtin_amdgcn_mfma_f32_16x16x32_fp8_fp8(
                        a[mt].l[s], b[nt].l[s], acc[mt][nt], 0, 0, 0);
        __syncthreads();
    }

    // Epilogue: score = p2[n] - 2*xp. Only the min VALUE per class is needed
    // (gathered-prototype distance == the min score + x2; indices are redundant).
    // C/D layout: col = lane&15, row = quad*4 + reg.
    float pg[4];
#pragma unroll
    for (int nt = 0; nt < 4; ++nt) pg[nt] = p2[n0 + wn * 64 + nt * 16 + mrow];

#pragma unroll
    for (int ch = 0; ch < 2; ++ch) {
        const int cls = bx * 4 + wn * 2 + ch;
#pragma unroll
        for (int mt = 0; mt < 4; ++mt)
#pragma unroll
            for (int reg = 0; reg < 4; ++reg) {
                float v = fminf(pg[ch * 2]     - 2.0f * acc[mt][ch * 2][reg],
                                pg[ch * 2 + 1] - 2.0f * acc[mt][ch * 2 + 1][reg]);
#pragma unroll
                for (int m = 8; m >= 1; m >>= 1) v = fminf(v, __shfl_xor(v, m));
                if (mrow == 0) {
                    int grow = m0 + wm * 64 + mt * 16 + quad * 4 + reg;
                    min_d[grow * C_ + cls] = v;
                }
            }
    }
}

// ---------- per-sample: target value + masked min over wrong classes (values only) ----------
__global__ void select_kernel(const float* __restrict__ min_d, const float* __restrict__ x2,
                              const int* __restrict__ tgt,
                              float* __restrict__ stw, float* __restrict__ sww) {
    int b    = blockIdx.x * 4 + (threadIdx.x >> 6);
    int lane = threadIdx.x & 63;
    int tc   = tgt[b];
    const float* row = min_d + (size_t)b * C_;

    float vt = row[tc];          // broadcast load
    float bw = 3.4e38f;
    for (int c = lane; c < C_; c += 64) {
        float v = row[c];
        if (c != tc) bw = fminf(bw, v);
    }
#pragma unroll
    for (int m = 32; m >= 1; m >>= 1) bw = fminf(bw, __shfl_xor(bw, m));
    if (lane == 0) {
        float xx = x2[b];
        stw[b] = xx + vt;        // = ||x - p_target*||^2 (fp8-dot approx)
        sww[b] = xx + bw;        // = ||x - p_wrong*||^2
    }
}

// Single-block reduction of 2x4096 floats + final loss
__global__ __launch_bounds__(1024)
void finalize_kernel(const float* __restrict__ stw, const float* __restrict__ sww,
                     float* __restrict__ out) {
    __shared__ float r1[16], r2[16];
    int tid = threadIdx.x;
    float s1 = 0.f, s2 = 0.f;
#pragma unroll
    for (int i = 0; i < 4; ++i) {
        s1 += stw[tid + i * 1024];
        s2 += sww[tid + i * 1024];
    }
#pragma unroll
    for (int m = 32; m >= 1; m >>= 1) { s1 += __shfl_xor(s1, m); s2 += __shfl_xor(s2, m); }
    if ((tid & 63) == 0) { r1[tid >> 6] = s1; r2[tid >> 6] = s2; }
    __syncthreads();
    if (tid == 0) {
        double t1 = 0.0, t2 = 0.0;
#pragma unroll
        for (int i = 0; i < 16; ++i) { t1 += (double)r1[i]; t2 += (double)r2[i]; }
        double denom = (double)B_ * (double)F_;
        double tl  = t1 / denom;
        double ntl = t2 / denom;
        out[0] = (float)((1.0 - ALPHA_) * tl + ALPHA_ / (ntl + EPS_));
    }
}

// ---------- launch ----------
extern "C" void kernel_launch(void* const* d_in, const int* in_sizes, int n_in,
                              void* d_out, int out_size, void* d_ws, size_t ws_size,
                              hipStream_t stream) {
    const float* outputs  = (const float*)d_in[0];
    const float* clusters = (const float*)d_in[1];
    const int*   tgt      = (const int*)d_in[2];
    float* out = (float*)d_out;

    char* ws = (char*)d_ws;
    // workspace layout (16B-aligned), total 8,692,736 bytes
    u8*     At      = (u8*)(ws);                     // packed A: 2,097,152
    u8*     Bt      = (u8*)(ws + 2097152);           // packed B: 3,276,800
    float*  sumsq   = (float*)(ws + 5373952);        // 10496*4 = 41,984 (x2 | p2)
    float*  min_d   = (float*)(ws + 5415936);        // 4096*200*4 = 3,276,800
    float*  x2      = sumsq;
    float*  p2      = sumsq + B_;
    // per-sample partials: reuse the At region (dead after score_kernel)
    float*  stw     = (float*)(ws);                  // 4096*4
    float*  sww     = (float*)(ws + 16384);          // 4096*4

    zero_kernel<<<NROWS_ / 256, 256, 0, stream>>>(sumsq);                                   // 41 blocks
    prep_kernel<<<(B_ * 32 + N_ * 32) / 256, 256, 0, stream>>>(outputs, clusters, At, Bt, sumsq); // 1312
    score_kernel<<<dim3(N_ / BN, B_ / BM), 256, 0, stream>>>(At, Bt, p2, min_d);            // 50x32
    select_kernel<<<B_ / 4, 256, 0, stream>>>(min_d, x2, tgt, stw, sww);                    // 1024
    finalize_kernel<<<1, 1024, 0, stream>>>(stw, sww, out);
}